// Round 1
// baseline (2841.936 us; speedup 1.0000x reference)
//
#include <hip/hip_runtime.h>
#include <hip/hip_bf16.h>

typedef __hip_bfloat16 bf16;

#define SEQ 256
#define NB  64
#define NV  300
#define NH  256
#define G3  768
#define D2  512
#define COLS 1536
#define ROWS 16384

__device__ __forceinline__ float sigm(float x){ return 1.0f/(1.0f+__expf(-x)); }
__device__ __forceinline__ float tanh_(float x){ float e=__expf(2.0f*x); return 1.0f-2.0f/(e+1.0f); }

// shared 64x64-tile fp32 GEMM inner product: As/Bs are [k][row] so reads are float4
__device__ __forceinline__ void mm16(const float (*As)[68], const float (*Bs)[68],
                                     float acc[4][4], int ty, int tx){
  #pragma unroll
  for (int kk=0;kk<16;kk++){
    const float4 a4 = *(const float4*)&As[kk][ty*4];
    const float4 b4 = *(const float4*)&Bs[kk][tx*4];
    const float ai[4] = {a4.x,a4.y,a4.z,a4.w};
    const float bj[4] = {b4.x,b4.y,b4.z,b4.w};
    #pragma unroll
    for (int i=0;i<4;i++)
      #pragma unroll
      for (int j=0;j<4;j++)
        acc[i][j] = fmaf(ai[i], bj[j], acc[i][j]);
  }
}

// --- prep: W_hh -> k-major vectorized layout Wv[dir][k/4][g][k%4] (fp32) ---
__global__ __launch_bounds__(256) void k_whh(const float* __restrict__ Wf,
                                             const float* __restrict__ Wb,
                                             float* __restrict__ Wv){
  int idx = blockIdx.x*256 + threadIdx.x;       // 2*768*256 = 393216
  int dir = idx / (G3*NH);
  int rem = idx - dir*(G3*NH);
  int g = rem / NH;
  int k = rem - g*NH;
  const float* W = dir ? Wb : Wf;
  Wv[((size_t)(dir*64 + (k>>2))*G3 + g)*4 + (k&3)] = W[(size_t)g*NH + k];
}

// --- xg = gather(embed, x) @ W_ih^T + b_ih, stored bf16 [s][row][1536] ---
__global__ __launch_bounds__(256) void k_xg(const int* __restrict__ x,
    const float* __restrict__ embed,
    const float* __restrict__ Wf, const float* __restrict__ Wb,
    const float* __restrict__ bf_, const float* __restrict__ bb_,
    bf16* __restrict__ xg)
{
  __shared__ float As[16][68];
  __shared__ float Bs[16][68];
  const int tid = threadIdx.x;
  const int R0 = blockIdx.x * 64;       // 512 row tiles over 2 docs * 16384 rows
  const int s  = R0 >> 14;
  const int r0 = R0 & 16383;
  const int C0 = blockIdx.y * 64;       // 24 col tiles over 1536 cols
  const int dir = C0 / G3;
  const int cg0 = C0 - dir*G3;
  const float* __restrict__ W  = dir ? Wb : Wf;
  const float* __restrict__ bi = dir ? bb_ : bf_;

  const int lr = tid >> 2;              // 0..63
  const int lk = (tid & 3) * 4;         // 0,4,8,12
  const int rr = r0 + lr;
  const int bidx = rr >> 8, nidx = rr & 255;
  const int token = x[(bidx*2 + s)*SEQ + nidx];
  const float* __restrict__ arow = embed + (size_t)token * NV;
  const float* __restrict__ brow = W + (size_t)(cg0 + lr) * NV;

  const int ty = tid >> 4, tx = tid & 15;
  float acc[4][4] = {};

  for (int k0 = 0; k0 < NV; k0 += 16){
    float av[4], bv[4];
    const int ka = k0 + lk;
    if (ka + 4 <= NV){
      float4 t = *(const float4*)(arow + ka);
      av[0]=t.x; av[1]=t.y; av[2]=t.z; av[3]=t.w;
      float4 u = *(const float4*)(brow + ka);
      bv[0]=u.x; bv[1]=u.y; bv[2]=u.z; bv[3]=u.w;
    } else {
      #pragma unroll
      for (int i=0;i<4;i++){
        av[i] = (ka+i < NV) ? arow[ka+i] : 0.0f;
        bv[i] = (ka+i < NV) ? brow[ka+i] : 0.0f;
      }
    }
    __syncthreads();
    #pragma unroll
    for (int i=0;i<4;i++){ As[lk+i][lr] = av[i]; Bs[lk+i][lr] = bv[i]; }
    __syncthreads();
    mm16(As, Bs, acc, ty, tx);
  }

  #pragma unroll
  for (int i=0;i<4;i++){
    const int r = r0 + ty*4 + i;
    #pragma unroll
    for (int j=0;j<4;j++){
      const int c = C0 + tx*4 + j;
      const float v = acc[i][j] + bi[cg0 + tx*4 + j];
      xg[((size_t)s*ROWS + r)*COLS + c] = __float2bfloat16(v);
    }
  }
}

// --- GRU recurrence: 64 WGs = 4 chains(doc,dir) x 16 batch-chunks of 4 ---
__global__ __launch_bounds__(256) void k_gru(const bf16* __restrict__ xg,
      const float* __restrict__ Wv,
      const float* __restrict__ bhf, const float* __restrict__ bhb,
      float* __restrict__ o2)
{
  const int tid = threadIdx.x;          // hidden unit
  const int wg = blockIdx.x;
  const int chain = wg >> 4;            // 0..3
  const int s = chain >> 1, dir = chain & 1;
  const int b0 = (wg & 15) * 4;
  const float* __restrict__ bhh = dir ? bhb : bhf;
  const float4* __restrict__ wv = (const float4*)Wv + (size_t)dir*64*G3;
  const bf16* __restrict__ xbase = xg + (size_t)s*ROWS*COLS + (size_t)dir*G3;
  float* __restrict__ obase = o2 + (size_t)s*NB*SEQ*D2 + (size_t)dir*NH;

  __shared__ float hbuf[2][4][NH];      // double-buffered hidden state
  #pragma unroll
  for (int b=0;b<4;b++) hbuf[0][b][tid] = 0.0f;
  __syncthreads();

  const float bh_r = bhh[tid], bh_z = bhh[NH+tid], bh_n = bhh[2*NH+tid];

  // register double-buffered weights, 4 k-groups (16 k) per buffer
  float4 wbuf[2][3][4];
  #pragma unroll
  for (int u=0;u<4;u++){
    wbuf[0][0][u] = wv[(size_t)u*G3 + tid];
    wbuf[0][1][u] = wv[(size_t)u*G3 + NH + tid];
    wbuf[0][2][u] = wv[(size_t)u*G3 + 2*NH + tid];
  }

  for (int t=0;t<SEQ;t++){
    const int n = dir ? (SEQ-1-t) : t;
    const int cur = t & 1;
    float ar[4]={0,0,0,0}, az[4]={0,0,0,0}, an_[4]={0,0,0,0};

    #pragma unroll 1
    for (int kgg2=0; kgg2<8; kgg2++){
      // ---- half A: prefetch group (2*kgg2+1) into buf1, compute group 2*kgg2 from buf0
      {
        const int nk = (2*kgg2 + 1) * 4;
        #pragma unroll
        for (int u=0;u<4;u++){
          wbuf[1][0][u] = wv[(size_t)(nk+u)*G3 + tid];
          wbuf[1][1][u] = wv[(size_t)(nk+u)*G3 + NH + tid];
          wbuf[1][2][u] = wv[(size_t)(nk+u)*G3 + 2*NH + tid];
        }
        #pragma unroll
        for (int u=0;u<4;u++){
          const int kk4 = (2*kgg2)*16 + u*4;
          const float4 wr = wbuf[0][0][u], wz = wbuf[0][1][u], wn = wbuf[0][2][u];
          #pragma unroll
          for (int b=0;b<4;b++){
            const float4 hv = *(const float4*)&hbuf[cur][b][kk4];
            ar[b]  = fmaf(wr.x,hv.x, fmaf(wr.y,hv.y, fmaf(wr.z,hv.z, fmaf(wr.w,hv.w, ar[b]))));
            az[b]  = fmaf(wz.x,hv.x, fmaf(wz.y,hv.y, fmaf(wz.z,hv.z, fmaf(wz.w,hv.w, az[b]))));
            an_[b] = fmaf(wn.x,hv.x, fmaf(wn.y,hv.y, fmaf(wn.z,hv.z, fmaf(wn.w,hv.w, an_[b]))));
          }
        }
      }
      // ---- half B: prefetch group (2*kgg2+2)&15 into buf0, compute group 2*kgg2+1 from buf1
      {
        const int nk = ((2*kgg2 + 2) & 15) * 4;   // wraps to group 0 for next step
        #pragma unroll
        for (int u=0;u<4;u++){
          wbuf[0][0][u] = wv[(size_t)(nk+u)*G3 + tid];
          wbuf[0][1][u] = wv[(size_t)(nk+u)*G3 + NH + tid];
          wbuf[0][2][u] = wv[(size_t)(nk+u)*G3 + 2*NH + tid];
        }
        #pragma unroll
        for (int u=0;u<4;u++){
          const int kk4 = (2*kgg2+1)*16 + u*4;
          const float4 wr = wbuf[1][0][u], wz = wbuf[1][1][u], wn = wbuf[1][2][u];
          #pragma unroll
          for (int b=0;b<4;b++){
            const float4 hv = *(const float4*)&hbuf[cur][b][kk4];
            ar[b]  = fmaf(wr.x,hv.x, fmaf(wr.y,hv.y, fmaf(wr.z,hv.z, fmaf(wr.w,hv.w, ar[b]))));
            az[b]  = fmaf(wz.x,hv.x, fmaf(wz.y,hv.y, fmaf(wz.z,hv.z, fmaf(wz.w,hv.w, az[b]))));
            an_[b] = fmaf(wn.x,hv.x, fmaf(wn.y,hv.y, fmaf(wn.z,hv.z, fmaf(wn.w,hv.w, an_[b]))));
          }
        }
      }
    }

    #pragma unroll
    for (int b=0;b<4;b++){
      const size_t xrow = ((size_t)(b0+b)*SEQ + n)*COLS;
      const float xr = __bfloat162float(xbase[xrow + tid]);
      const float xz = __bfloat162float(xbase[xrow + NH + tid]);
      const float xn = __bfloat162float(xbase[xrow + 2*NH + tid]);
      const float r = sigm(xr + ar[b] + bh_r);
      const float z = sigm(xz + az[b] + bh_z);
      const float nn = tanh_(xn + r*(an_[b] + bh_n));
      const float hprev = hbuf[cur][b][tid];
      const float hnew = (1.0f - z)*nn + z*hprev;
      hbuf[cur^1][b][tid] = hnew;
      obase[((size_t)(b0+b)*SEQ + n)*D2 + tid] = hnew;
    }
    __syncthreads();
  }
}

// --- scores[sb][n][m] = <o2[n], o2[m]> - (n-m)^2/sigma ---
__global__ __launch_bounds__(256) void k_scores(const float* __restrict__ o2,
                                                float* __restrict__ sc){
  __shared__ float An[16][68];
  __shared__ float Am[16][68];
  const int tid = threadIdx.x;
  const int sb = blockIdx.z;
  const int n0 = blockIdx.x*64, m0 = blockIdx.y*64;
  const float* __restrict__ O = o2 + (size_t)sb*SEQ*D2;
  const int lr = tid >> 2, lk = (tid & 3)*4;
  const int ty = tid >> 4, tx = tid & 15;
  float acc[4][4] = {};
  for (int k0=0;k0<D2;k0+=16){
    const float4 a = *(const float4*)(O + (size_t)(n0+lr)*D2 + k0 + lk);
    const float4 b = *(const float4*)(O + (size_t)(m0+lr)*D2 + k0 + lk);
    __syncthreads();
    An[lk+0][lr]=a.x; An[lk+1][lr]=a.y; An[lk+2][lr]=a.z; An[lk+3][lr]=a.w;
    Am[lk+0][lr]=b.x; Am[lk+1][lr]=b.y; Am[lk+2][lr]=b.z; Am[lk+3][lr]=b.w;
    __syncthreads();
    mm16(An, Am, acc, ty, tx);
  }
  #pragma unroll
  for (int i=0;i<4;i++){
    const int nn = n0 + ty*4 + i;
    #pragma unroll
    for (int j=0;j<4;j++){
      const int mm = m0 + tx*4 + j;
      const float d = (float)(nn - mm);
      sc[((size_t)sb*SEQ + nn)*SEQ + mm] = acc[i][j] - d*d*(1.0f/0.95f);
    }
  }
}

// --- row softmax over last dim (256), one wave per row, in place ---
__global__ __launch_bounds__(256) void k_softmax(float* __restrict__ sc){
  const int row = blockIdx.x*4 + (threadIdx.x >> 6);
  const int lane = threadIdx.x & 63;
  float4* R = (float4*)(sc + (size_t)row*SEQ);
  float4 v = R[lane];
  float m = fmaxf(fmaxf(v.x,v.y), fmaxf(v.z,v.w));
  #pragma unroll
  for (int off=32; off; off>>=1) m = fmaxf(m, __shfl_xor(m, off));
  float4 e;
  e.x = __expf(v.x-m); e.y = __expf(v.y-m); e.z = __expf(v.z-m); e.w = __expf(v.w-m);
  float ssum = e.x+e.y+e.z+e.w;
  #pragma unroll
  for (int off=32; off; off>>=1) ssum += __shfl_xor(ssum, off);
  const float inv = 1.0f/ssum;
  e.x*=inv; e.y*=inv; e.z*=inv; e.w*=inv;
  R[lane] = e;
}

// --- o5 = P @ o2 per (s,b) ---
__global__ __launch_bounds__(256) void k_o5(const float* __restrict__ sc,
                                            const float* __restrict__ o2,
                                            float* __restrict__ o5){
  __shared__ float As[16][68];
  __shared__ float Bs[16][68];
  const int tid = threadIdx.x;
  const int sb = blockIdx.z;
  const int n0 = blockIdx.x*64, d0 = blockIdx.y*64;
  const float* __restrict__ P = sc + (size_t)sb*SEQ*SEQ;
  const float* __restrict__ O = o2 + (size_t)sb*SEQ*D2;
  const int lr = tid >> 2, lk = (tid & 3)*4;
  const int lc = tid & 63, lq = tid >> 6;
  const int ty = tid >> 4, tx = tid & 15;
  float acc[4][4] = {};
  for (int k0=0;k0<SEQ;k0+=16){
    const float4 a = *(const float4*)(P + (size_t)(n0+lr)*SEQ + k0 + lk);
    float bv[4];
    #pragma unroll
    for (int i=0;i<4;i++) bv[i] = O[(size_t)(k0 + lq*4 + i)*D2 + d0 + lc];
    __syncthreads();
    As[lk+0][lr]=a.x; As[lk+1][lr]=a.y; As[lk+2][lr]=a.z; As[lk+3][lr]=a.w;
    #pragma unroll
    for (int i=0;i<4;i++) Bs[lq*4+i][lc] = bv[i];
    __syncthreads();
    mm16(As, Bs, acc, ty, tx);
  }
  #pragma unroll
  for (int i=0;i<4;i++)
    #pragma unroll
    for (int j=0;j<4;j++)
      o5[(size_t)sb*SEQ*D2 + (size_t)(n0+ty*4+i)*D2 + d0+tx*4+j] = acc[i][j];
}

// --- mean/max pool over n: feats[sb][0:512]=mean, [512:1024]=max ---
__global__ __launch_bounds__(256) void k_pool(const float* __restrict__ o5,
                                              float* __restrict__ feats){
  const int idx = blockIdx.x*256 + threadIdx.x;  // 128*512
  const int sb = idx >> 9, d = idx & 511;
  const float* __restrict__ P = o5 + (size_t)sb*SEQ*D2 + d;
  float sum = 0.0f, mx = -1e30f;
  for (int n=0;n<SEQ;n++){ const float v = P[(size_t)n*D2]; sum += v; mx = fmaxf(mx, v); }
  feats[(size_t)sb*1024 + d] = sum*(1.0f/256.0f);
  feats[(size_t)sb*1024 + 512 + d] = mx;
}

// --- z = [|fa-fb|, fa*fb] ---
__global__ __launch_bounds__(256) void k_z(const float* __restrict__ feats,
                                           float* __restrict__ Z){
  const int idx = blockIdx.x*256 + threadIdx.x;  // 64*2048
  const int b = idx >> 11, k = idx & 2047;
  const int j = (k < 1024) ? k : (k - 1024);
  const float fa = feats[(size_t)b*1024 + j];
  const float fb = feats[(size_t)(64 + b)*1024 + j];
  Z[idx] = (k < 1024) ? fabsf(fa - fb) : fa*fb;
}

// --- h1 = relu(Z @ fc1_w^T + fc1_b), M=64 N=512 K=2048 ---
__global__ __launch_bounds__(256) void k_fc1(const float* __restrict__ Z,
                                             const float* __restrict__ w,
                                             const float* __restrict__ bias,
                                             float* __restrict__ h1){
  __shared__ float As[16][68];
  __shared__ float Bs[16][68];
  const int tid = threadIdx.x;
  const int c0 = blockIdx.x*64;   // 8 col tiles
  const int lr = tid >> 2, lk = (tid & 3)*4;
  const int ty = tid >> 4, tx = tid & 15;
  float acc[4][4] = {};
  for (int k0=0;k0<2048;k0+=16){
    const float4 a = *(const float4*)(Z + (size_t)lr*2048 + k0 + lk);
    const float4 b = *(const float4*)(w + (size_t)(c0+lr)*2048 + k0 + lk);
    __syncthreads();
    As[lk+0][lr]=a.x; As[lk+1][lr]=a.y; As[lk+2][lr]=a.z; As[lk+3][lr]=a.w;
    Bs[lk+0][lr]=b.x; Bs[lk+1][lr]=b.y; Bs[lk+2][lr]=b.z; Bs[lk+3][lr]=b.w;
    __syncthreads();
    mm16(As, Bs, acc, ty, tx);
  }
  #pragma unroll
  for (int i=0;i<4;i++)
    #pragma unroll
    for (int j=0;j<4;j++)
      h1[(size_t)(ty*4+i)*512 + c0+tx*4+j] = fmaxf(acc[i][j] + bias[c0+tx*4+j], 0.0f);
}

// --- out[b] = sigmoid(h1[b] . fc2_w + fc2_b) ---
__global__ __launch_bounds__(256) void k_fc2(const float* __restrict__ h1,
                                             const float* __restrict__ w2,
                                             const float* __restrict__ b2,
                                             float* __restrict__ out){
  __shared__ float red[256];
  const int b = blockIdx.x, tid = threadIdx.x;
  float p = h1[(size_t)b*512 + tid]*w2[tid] + h1[(size_t)b*512 + 256 + tid]*w2[256 + tid];
  red[tid] = p; __syncthreads();
  for (int s2=128; s2; s2>>=1){ if (tid < s2) red[tid] += red[tid+s2]; __syncthreads(); }
  if (tid == 0) out[b] = 1.0f/(1.0f + __expf(-(red[0] + b2[0])));
}

extern "C" void kernel_launch(void* const* d_in, const int* in_sizes, int n_in,
                              void* d_out, int out_size, void* d_ws, size_t ws_size,
                              hipStream_t stream){
  const int*   x     = (const int*)d_in[0];
  const float* embed = (const float*)d_in[1];
  const float* Wihf  = (const float*)d_in[2];
  const float* Whhf  = (const float*)d_in[3];
  const float* bihf  = (const float*)d_in[4];
  const float* bhhf  = (const float*)d_in[5];
  const float* Wihb  = (const float*)d_in[6];
  const float* Whhb  = (const float*)d_in[7];
  const float* bihb  = (const float*)d_in[8];
  const float* bhhb  = (const float*)d_in[9];
  const float* fc1w  = (const float*)d_in[10];
  const float* fc1b  = (const float*)d_in[11];
  const float* fc2w  = (const float*)d_in[12];
  const float* fc2b  = (const float*)d_in[13];
  float* out = (float*)d_out;

  char* ws = (char*)d_ws;
  // layout (bytes):
  //   [0, 100663296)           xg bf16 [2][16384][1536]   (dead after k_gru)
  //     alias [0, 33554432)    scores fp32 [128][256][256]
  //     alias [33554432, 100663296) o5 fp32 [128][256][512]
  //   [100663296, 167772160)   o2 fp32 [128][256][512]
  //   [167772160, 169345024)   Wv fp32 [2][64][768][4]
  //   [169345024, 169869312)   feats fp32 [128][1024]
  //   [169869312, 170393600)   Z fp32 [64][2048]
  //   [170393600, 170524672)   h1 fp32 [64][512]
  bf16*  xg     = (bf16*)ws;
  float* scores = (float*)ws;
  float* o5     = (float*)(ws + 33554432);
  float* o2     = (float*)(ws + 100663296);
  float* Wv     = (float*)(ws + 167772160);
  float* feats  = (float*)(ws + 169345024);
  float* Z      = (float*)(ws + 169869312);
  float* h1     = (float*)(ws + 170393600);

  k_whh<<<1536, 256, 0, stream>>>(Whhf, Whhb, Wv);
  k_xg<<<dim3(512, 24), 256, 0, stream>>>(x, embed, Wihf, Wihb, bihf, bihb, xg);
  k_gru<<<64, 256, 0, stream>>>(xg, Wv, bhhf, bhhb, o2);
  k_scores<<<dim3(4, 4, 128), 256, 0, stream>>>(o2, scores);
  k_softmax<<<8192, 256, 0, stream>>>(scores);
  k_o5<<<dim3(4, 8, 128), 256, 0, stream>>>(scores, o2, o5);
  k_pool<<<256, 256, 0, stream>>>(o5, feats);
  k_z<<<512, 256, 0, stream>>>(feats, Z);
  k_fc1<<<8, 256, 0, stream>>>(Z, fc1w, fc1b, h1);
  k_fc2<<<64, 256, 0, stream>>>(h1, fc2w, fc2b, out);
}

// Round 2
// 2596.130 us; speedup vs baseline: 1.0947x; 1.0947x over previous
//
#include <hip/hip_runtime.h>
#include <hip/hip_bf16.h>

typedef __hip_bfloat16 bf16;
typedef __bf16 bf16x8 __attribute__((ext_vector_type(8)));
typedef float f32x4 __attribute__((ext_vector_type(4)));

#define SEQ 256
#define NB  64
#define NV  300
#define NH  256
#define G3  768
#define D2  512
#define COLS 1536
#define ROWS 16384

__device__ __forceinline__ float sigm(float x){ return 1.0f/(1.0f+__expf(-x)); }
__device__ __forceinline__ float tanh_(float x){ float e=__expf(2.0f*x); return 1.0f-2.0f/(e+1.0f); }

__device__ __forceinline__ void gld_lds16(const void* g, void* l){
  __builtin_amdgcn_global_load_lds((__attribute__((address_space(1))) void*)g,
                                   (__attribute__((address_space(3))) void*)l, 16, 0, 0);
}

// shared 64x64-tile fp32 GEMM inner product: As/Bs are [k][row] so reads are float4
__device__ __forceinline__ void mm16(const float (*As)[68], const float (*Bs)[68],
                                     float acc[4][4], int ty, int tx){
  #pragma unroll
  for (int kk=0;kk<16;kk++){
    const float4 a4 = *(const float4*)&As[kk][ty*4];
    const float4 b4 = *(const float4*)&Bs[kk][tx*4];
    const float ai[4] = {a4.x,a4.y,a4.z,a4.w};
    const float bj[4] = {b4.x,b4.y,b4.z,b4.w};
    #pragma unroll
    for (int i=0;i<4;i++)
      #pragma unroll
      for (int j=0;j<4;j++)
        acc[i][j] = fmaf(ai[i], bj[j], acc[i][j]);
  }
}

// --- prep: W_hh -> bf16 MFMA B-frag layout ---
// Wpk[dir][w][nt][kf][lane] = 8 bf16: B[k][col] with col=lane&15 -> gate
//   gate g = tau*256 + w*64 + usub*16 + (lane&15), nt = tau*4+usub
//   k = kf*32 + (lane>>4)*8 + e
__global__ __launch_bounds__(256) void k_wpk(const float* __restrict__ Wf,
                                             const float* __restrict__ Wb,
                                             ushort* __restrict__ wpk){
  const int idx = blockIdx.x*256 + threadIdx.x;   // 49152
  const int l   = idx & 63;
  const int r1  = idx >> 6;
  const int kf  = r1 & 7;
  const int r2  = r1 >> 3;
  const int nt  = r2 % 12;
  const int r3  = r2 / 12;
  const int w   = r3 & 3;
  const int dir = r3 >> 2;
  const int tau = nt >> 2, usub = nt & 3;
  const int g   = tau*256 + w*64 + usub*16 + (l & 15);
  const int kb  = kf*32 + (l >> 4)*8;
  const float* __restrict__ W = dir ? Wb : Wf;
  #pragma unroll
  for (int e=0;e<8;e++){
    __bf16 v = (__bf16)W[(size_t)g*NH + kb + e];
    wpk[(size_t)idx*8 + e] = *(ushort*)&v;
  }
}

// --- xg = gather(embed, x) @ W_ih^T + b_ih, stored bf16, columns swizzled:
//     store col = dir*768 + tau*256 + ((u + 4*(batch&15)) & 255)
__global__ __launch_bounds__(256) void k_xg(const int* __restrict__ x,
    const float* __restrict__ embed,
    const float* __restrict__ Wf, const float* __restrict__ Wb,
    const float* __restrict__ bf_, const float* __restrict__ bb_,
    bf16* __restrict__ xg)
{
  __shared__ float As[16][68];
  __shared__ float Bs[16][68];
  const int tid = threadIdx.x;
  const int R0 = blockIdx.x * 64;
  const int s  = R0 >> 14;
  const int r0 = R0 & 16383;
  const int C0 = blockIdx.y * 64;
  const int dir = C0 / G3;
  const int cg0 = C0 - dir*G3;
  const float* __restrict__ W  = dir ? Wb : Wf;
  const float* __restrict__ bi = dir ? bb_ : bf_;

  const int lr = tid >> 2;
  const int lk = (tid & 3) * 4;
  const int rr = r0 + lr;
  const int bidx = rr >> 8, nidx = rr & 255;
  const int token = x[(bidx*2 + s)*SEQ + nidx];
  const float* __restrict__ arow = embed + (size_t)token * NV;
  const float* __restrict__ brow = W + (size_t)(cg0 + lr) * NV;

  const int ty = tid >> 4, tx = tid & 15;
  float acc[4][4] = {};

  for (int k0 = 0; k0 < NV; k0 += 16){
    float av[4], bv[4];
    const int ka = k0 + lk;
    if (ka + 4 <= NV){
      float4 t = *(const float4*)(arow + ka);
      av[0]=t.x; av[1]=t.y; av[2]=t.z; av[3]=t.w;
      float4 u = *(const float4*)(brow + ka);
      bv[0]=u.x; bv[1]=u.y; bv[2]=u.z; bv[3]=u.w;
    } else {
      #pragma unroll
      for (int i=0;i<4;i++){
        av[i] = (ka+i < NV) ? arow[ka+i] : 0.0f;
        bv[i] = (ka+i < NV) ? brow[ka+i] : 0.0f;
      }
    }
    __syncthreads();
    #pragma unroll
    for (int i=0;i<4;i++){ As[lk+i][lr] = av[i]; Bs[lk+i][lr] = bv[i]; }
    __syncthreads();
    mm16(As, Bs, acc, ty, tx);
  }

  #pragma unroll
  for (int i=0;i<4;i++){
    const int r = r0 + ty*4 + i;
    const int bl = (r >> 8) & 15;
    #pragma unroll
    for (int j=0;j<4;j++){
      const int c = C0 + tx*4 + j;
      const int cw = c - dir*G3;
      const int tau = cw >> 8, u = cw & 255;
      const float v = acc[i][j] + bi[cg0 + tx*4 + j];
      const int cs = dir*G3 + tau*256 + ((u + 4*bl) & 255);
      xg[((size_t)s*ROWS + r)*COLS + cs] = __float2bfloat16(v);
    }
  }
}

// --- GRU recurrence: 16 WGs = 4 chains x 4 batch-slices of 16; MFMA + resident weights ---
// LDS: [0,98304) W kf=6,7 slices; [98304,122880) xbuf 16x1536B; [122880,139776) h dbuf 2x16x528B
#define XB 98304
#define HB 122880
__global__ __launch_bounds__(256, 1) void k_gru(const bf16* __restrict__ xg,
      const ushort* __restrict__ wpk,
      const float* __restrict__ bhhf, const float* __restrict__ bhhb,
      float* __restrict__ o2)
{
  __shared__ __align__(16) char SMEM[139776];
  const int tid = threadIdx.x, w = tid >> 6, l = tid & 63, l15 = l & 15, lg = l >> 4;
  const int wgid = blockIdx.x;
  const int chain = wgid >> 2, slice = wgid & 3;
  const int s = chain >> 1, dir = chain & 1, b0 = slice * 16;
  const int sb64 = s*64 + b0;
  const float* __restrict__ bhh = dir ? bhhb : bhhf;
  const char* wpkb = (const char*)wpk;
  const char* wbg  = wpkb + (size_t)(dir*4 + w) * 98304;   // 12*8*64*16 per (dir,w)
  const char* xgw  = (const char*)xg + (size_t)s*50331648 + dir*1536;

  const int u0 = w*64 + l15;
  const int aoff = l15*528 + lg*16;
  const int wbase = w*24576 + l*16;

  // staging map: chunk ci = i*256+tid -> (row bl, 16B off)
  int sb_[6], dst_[6];
  #pragma unroll
  for (int i=0;i<6;i++){
    const int ci = i*256 + tid;
    const int bl = ci/96, off = ci - bl*96;
    sb_[i] = (b0+bl)*786432 + off*16;
    dst_[i] = XB + ci*16;
  }

  // zero h buffer 0
  for (int k=tid; k<2112; k+=256) *(float*)&SMEM[HB + k*4] = 0.0f;

  // W kf=6,7 -> LDS (once)
  #pragma unroll
  for (int nt=0;nt<12;nt++)
    #pragma unroll
    for (int kfi=0;kfi<2;kfi++)
      gld_lds16(wbg + (size_t)(((nt*8 + 6 + kfi)*64) + l)*16,
                &SMEM[(w*24 + nt*2 + kfi)*1024]);

  // resident W kf=0..5 (288 VGPRs)
  bf16x8 Wr[12][6];
  #pragma unroll
  for (int nt=0;nt<12;nt++)
    #pragma unroll
    for (int kf=0;kf<6;kf++)
      Wr[nt][kf] = *(const bf16x8*)(wbg + (size_t)((nt*8+kf)*64 + l)*16);

  // biases
  float br[4], bz[4], bn[4];
  #pragma unroll
  for (int m=0;m<4;m++){
    br[m] = bhh[u0 + m*16];
    bz[m] = bhh[256 + u0 + m*16];
    bn[m] = bhh[512 + u0 + m*16];
  }

  // stage step 0 xg
  {
    const int n0 = dir ? 255 : 0;
    uint4 sreg[6];
    #pragma unroll
    for (int i=0;i<6;i++) sreg[i] = *(const uint4*)(xgw + sb_[i] + (size_t)n0*3072);
    #pragma unroll
    for (int i=0;i<6;i++) *(uint4*)&SMEM[dst_[i]] = sreg[i];
  }
  __syncthreads();

  float hp[4][4] = {};

  #pragma unroll 1
  for (int t=0; t<SEQ; ++t){
    const int cur = t & 1;
    const int n = dir ? (255 - t) : t;
    const int hcur = HB + cur*8448, hnxt = HB + (cur^1)*8448;

    // issue next-step xg loads early (T14)
    uint4 sreg[6];
    if (t < 255){
      const int n2 = dir ? (254 - t) : (t + 1);
      #pragma unroll
      for (int i=0;i<6;i++) sreg[i] = *(const uint4*)(xgw + sb_[i] + (size_t)n2*3072);
    }

    // hg = h_t @ W_hh^T  (MFMA, bf16 in / fp32 out)
    f32x4 C[12] = {};
    #pragma unroll
    for (int kf=0;kf<6;kf++){
      const bf16x8 a = *(const bf16x8*)&SMEM[hcur + aoff + kf*64];
      #pragma unroll
      for (int nt=0;nt<12;nt++)
        C[nt] = __builtin_amdgcn_mfma_f32_16x16x32_bf16(a, Wr[nt][kf], C[nt], 0, 0, 0);
    }
    #pragma unroll
    for (int kfi=0;kfi<2;kfi++){
      const bf16x8 a = *(const bf16x8*)&SMEM[hcur + aoff + (6+kfi)*64];
      #pragma unroll
      for (int nt=0;nt<12;nt++){
        const bf16x8 wv = *(const bf16x8*)&SMEM[wbase + nt*2048 + kfi*1024];
        C[nt] = __builtin_amdgcn_mfma_f32_16x16x32_bf16(a, wv, C[nt], 0, 0, 0);
      }
    }

    // gates + h update (fp32 carried state in regs)
    #pragma unroll
    for (int m=0;m<4;m++){
      #pragma unroll
      for (int j=0;j<4;j++){
        const int rb = lg*4 + j;
        const int usw = (u0 + m*16 + 4*rb) & 255;
        const int xb = XB + rb*1536 + usw*2;
        const float xr = (float)*(const __bf16*)&SMEM[xb];
        const float xz = (float)*(const __bf16*)&SMEM[xb + 512];
        const float xn = (float)*(const __bf16*)&SMEM[xb + 1024];
        const float r  = sigm(xr + C[m][j]     + br[m]);
        const float z  = sigm(xz + C[4+m][j]   + bz[m]);
        const float nn = tanh_(xn + r*(C[8+m][j] + bn[m]));
        const float h  = (1.0f - z)*nn + z*hp[m][j];
        hp[m][j] = h;
        *(__bf16*)&SMEM[hnxt + rb*528 + (u0 + m*16)*2] = (__bf16)h;
        o2[((size_t)(sb64 + rb)*256 + n)*512 + dir*256 + u0 + m*16] = h;
      }
    }
    __syncthreads();                 // xbuf reads done; h[nxt] visible
    if (t < 255){
      #pragma unroll
      for (int i=0;i<6;i++) *(uint4*)&SMEM[dst_[i]] = sreg[i];
      __syncthreads();               // xbuf(t+1) visible
    }
  }
}

// --- scores[sb][n][m] = <o2[n], o2[m]> - (n-m)^2/sigma ---
__global__ __launch_bounds__(256) void k_scores(const float* __restrict__ o2,
                                                float* __restrict__ sc){
  __shared__ float An[16][68];
  __shared__ float Am[16][68];
  const int tid = threadIdx.x;
  const int sb = blockIdx.z;
  const int n0 = blockIdx.x*64, m0 = blockIdx.y*64;
  const float* __restrict__ O = o2 + (size_t)sb*SEQ*D2;
  const int lr = tid >> 2, lk = (tid & 3)*4;
  const int ty = tid >> 4, tx = tid & 15;
  float acc[4][4] = {};
  for (int k0=0;k0<D2;k0+=16){
    const float4 a = *(const float4*)(O + (size_t)(n0+lr)*D2 + k0 + lk);
    const float4 b = *(const float4*)(O + (size_t)(m0+lr)*D2 + k0 + lk);
    __syncthreads();
    An[lk+0][lr]=a.x; An[lk+1][lr]=a.y; An[lk+2][lr]=a.z; An[lk+3][lr]=a.w;
    Am[lk+0][lr]=b.x; Am[lk+1][lr]=b.y; Am[lk+2][lr]=b.z; Am[lk+3][lr]=b.w;
    __syncthreads();
    mm16(An, Am, acc, ty, tx);
  }
  #pragma unroll
  for (int i=0;i<4;i++){
    const int nn = n0 + ty*4 + i;
    #pragma unroll
    for (int j=0;j<4;j++){
      const int mm = m0 + tx*4 + j;
      const float d = (float)(nn - mm);
      sc[((size_t)sb*SEQ + nn)*SEQ + mm] = acc[i][j] - d*d*(1.0f/0.95f);
    }
  }
}

// --- row softmax over last dim (256), one wave per row, in place ---
__global__ __launch_bounds__(256) void k_softmax(float* __restrict__ sc){
  const int row = blockIdx.x*4 + (threadIdx.x >> 6);
  const int lane = threadIdx.x & 63;
  float4* R = (float4*)(sc + (size_t)row*SEQ);
  float4 v = R[lane];
  float m = fmaxf(fmaxf(v.x,v.y), fmaxf(v.z,v.w));
  #pragma unroll
  for (int off=32; off; off>>=1) m = fmaxf(m, __shfl_xor(m, off));
  float4 e;
  e.x = __expf(v.x-m); e.y = __expf(v.y-m); e.z = __expf(v.z-m); e.w = __expf(v.w-m);
  float ssum = e.x+e.y+e.z+e.w;
  #pragma unroll
  for (int off=32; off; off>>=1) ssum += __shfl_xor(ssum, off);
  const float inv = 1.0f/ssum;
  e.x*=inv; e.y*=inv; e.z*=inv; e.w*=inv;
  R[lane] = e;
}

// --- o5 = P @ o2 per (s,b) ---
__global__ __launch_bounds__(256) void k_o5(const float* __restrict__ sc,
                                            const float* __restrict__ o2,
                                            float* __restrict__ o5){
  __shared__ float As[16][68];
  __shared__ float Bs[16][68];
  const int tid = threadIdx.x;
  const int sb = blockIdx.z;
  const int n0 = blockIdx.x*64, d0 = blockIdx.y*64;
  const float* __restrict__ P = sc + (size_t)sb*SEQ*SEQ;
  const float* __restrict__ O = o2 + (size_t)sb*SEQ*D2;
  const int lr = tid >> 2, lk = (tid & 3)*4;
  const int lc = tid & 63, lq = tid >> 6;
  const int ty = tid >> 4, tx = tid & 15;
  float acc[4][4] = {};
  for (int k0=0;k0<SEQ;k0+=16){
    const float4 a = *(const float4*)(P + (size_t)(n0+lr)*SEQ + k0 + lk);
    float bv[4];
    #pragma unroll
    for (int i=0;i<4;i++) bv[i] = O[(size_t)(k0 + lq*4 + i)*D2 + d0 + lc];
    __syncthreads();
    As[lk+0][lr]=a.x; As[lk+1][lr]=a.y; As[lk+2][lr]=a.z; As[lk+3][lr]=a.w;
    #pragma unroll
    for (int i=0;i<4;i++) Bs[lq*4+i][lc] = bv[i];
    __syncthreads();
    mm16(As, Bs, acc, ty, tx);
  }
  #pragma unroll
  for (int i=0;i<4;i++)
    #pragma unroll
    for (int j=0;j<4;j++)
      o5[(size_t)sb*SEQ*D2 + (size_t)(n0+ty*4+i)*D2 + d0+tx*4+j] = acc[i][j];
}

// --- mean/max pool over n ---
__global__ __launch_bounds__(256) void k_pool(const float* __restrict__ o5,
                                              float* __restrict__ feats){
  const int idx = blockIdx.x*256 + threadIdx.x;
  const int sb = idx >> 9, d = idx & 511;
  const float* __restrict__ P = o5 + (size_t)sb*SEQ*D2 + d;
  float sum = 0.0f, mx = -1e30f;
  for (int n=0;n<SEQ;n++){ const float v = P[(size_t)n*D2]; sum += v; mx = fmaxf(mx, v); }
  feats[(size_t)sb*1024 + d] = sum*(1.0f/256.0f);
  feats[(size_t)sb*1024 + 512 + d] = mx;
}

// --- z = [|fa-fb|, fa*fb] ---
__global__ __launch_bounds__(256) void k_z(const float* __restrict__ feats,
                                           float* __restrict__ Z){
  const int idx = blockIdx.x*256 + threadIdx.x;
  const int b = idx >> 11, k = idx & 2047;
  const int j = (k < 1024) ? k : (k - 1024);
  const float fa = feats[(size_t)b*1024 + j];
  const float fb = feats[(size_t)(64 + b)*1024 + j];
  Z[idx] = (k < 1024) ? fabsf(fa - fb) : fa*fb;
}

// --- h1 = relu(Z @ fc1_w^T + fc1_b) ---
__global__ __launch_bounds__(256) void k_fc1(const float* __restrict__ Z,
                                             const float* __restrict__ w,
                                             const float* __restrict__ bias,
                                             float* __restrict__ h1){
  __shared__ float As[16][68];
  __shared__ float Bs[16][68];
  const int tid = threadIdx.x;
  const int c0 = blockIdx.x*64;
  const int lr = tid >> 2, lk = (tid & 3)*4;
  const int ty = tid >> 4, tx = tid & 15;
  float acc[4][4] = {};
  for (int k0=0;k0<2048;k0+=16){
    const float4 a = *(const float4*)(Z + (size_t)lr*2048 + k0 + lk);
    const float4 b = *(const float4*)(w + (size_t)(c0+lr)*2048 + k0 + lk);
    __syncthreads();
    As[lk+0][lr]=a.x; As[lk+1][lr]=a.y; As[lk+2][lr]=a.z; As[lk+3][lr]=a.w;
    Bs[lk+0][lr]=b.x; Bs[lk+1][lr]=b.y; Bs[lk+2][lr]=b.z; Bs[lk+3][lr]=b.w;
    __syncthreads();
    mm16(As, Bs, acc, ty, tx);
  }
  #pragma unroll
  for (int i=0;i<4;i++)
    #pragma unroll
    for (int j=0;j<4;j++)
      h1[(size_t)(ty*4+i)*512 + c0+tx*4+j] = fmaxf(acc[i][j] + bias[c0+tx*4+j], 0.0f);
}

// --- out[b] = sigmoid(h1[b] . fc2_w + fc2_b) ---
__global__ __launch_bounds__(256) void k_fc2(const float* __restrict__ h1,
                                             const float* __restrict__ w2,
                                             const float* __restrict__ b2,
                                             float* __restrict__ out){
  __shared__ float red[256];
  const int b = blockIdx.x, tid = threadIdx.x;
  float p = h1[(size_t)b*512 + tid]*w2[tid] + h1[(size_t)b*512 + 256 + tid]*w2[256 + tid];
  red[tid] = p; __syncthreads();
  for (int s2=128; s2; s2>>=1){ if (tid < s2) red[tid] += red[tid+s2]; __syncthreads(); }
  if (tid == 0) out[b] = 1.0f/(1.0f + __expf(-(red[0] + b2[0])));
}

extern "C" void kernel_launch(void* const* d_in, const int* in_sizes, int n_in,
                              void* d_out, int out_size, void* d_ws, size_t ws_size,
                              hipStream_t stream){
  const int*   x     = (const int*)d_in[0];
  const float* embed = (const float*)d_in[1];
  const float* Wihf  = (const float*)d_in[2];
  const float* Whhf  = (const float*)d_in[3];
  const float* bihf  = (const float*)d_in[4];
  const float* bhhf  = (const float*)d_in[5];
  const float* Wihb  = (const float*)d_in[6];
  const float* Whhb  = (const float*)d_in[7];
  const float* bihb  = (const float*)d_in[8];
  const float* bhhb  = (const float*)d_in[9];
  const float* fc1w  = (const float*)d_in[10];
  const float* fc1b  = (const float*)d_in[11];
  const float* fc2w  = (const float*)d_in[12];
  const float* fc2b  = (const float*)d_in[13];
  float* out = (float*)d_out;

  char* ws = (char*)d_ws;
  // layout (bytes):
  //   [0, 100663296)           xg bf16 [2][16384][1536] swizzled cols (dead after k_gru)
  //     alias [0, 33554432)    scores fp32 [128][256][256]
  //     alias [33554432, 100663296) o5 fp32 [128][256][512]
  //   [100663296, 167772160)   o2 fp32 [128][256][512]
  //   [167772160, +786432)     Wpk bf16 frag-packed [2][4][12][8][64][8]
  //   [169345024, 169869312)   feats fp32 [128][1024]
  //   [169869312, 170393600)   Z fp32 [64][2048]
  //   [170393600, 170524672)   h1 fp32 [64][512]
  bf16*   xg     = (bf16*)ws;
  float*  scores = (float*)ws;
  float*  o5     = (float*)(ws + 33554432);
  float*  o2     = (float*)(ws + 100663296);
  ushort* Wpk    = (ushort*)(ws + 167772160);
  float*  feats  = (float*)(ws + 169345024);
  float*  Z      = (float*)(ws + 169869312);
  float*  h1     = (float*)(ws + 170393600);

  k_wpk<<<192, 256, 0, stream>>>(Whhf, Whhb, Wpk);
  k_xg<<<dim3(512, 24), 256, 0, stream>>>(x, embed, Wihf, Wihb, bihf, bihb, xg);
  k_gru<<<16, 256, 0, stream>>>(xg, Wpk, bhhf, bhhb, o2);
  k_scores<<<dim3(4, 4, 128), 256, 0, stream>>>(o2, scores);
  k_softmax<<<8192, 256, 0, stream>>>(scores);
  k_o5<<<dim3(4, 8, 128), 256, 0, stream>>>(scores, o2, o5);
  k_pool<<<256, 256, 0, stream>>>(o5, feats);
  k_z<<<512, 256, 0, stream>>>(feats, Z);
  k_fc1<<<8, 256, 0, stream>>>(Z, fc1w, fc1b, h1);
  k_fc2<<<64, 256, 0, stream>>>(h1, fc2w, fc2b, out);
}

// Round 3
// 1511.262 us; speedup vs baseline: 1.8805x; 1.7179x over previous
//
#include <hip/hip_runtime.h>
#include <hip/hip_bf16.h>

typedef __hip_bfloat16 bf16;
typedef __bf16 bf16x8 __attribute__((ext_vector_type(8)));
typedef float f32x4 __attribute__((ext_vector_type(4)));

#define SEQ 256
#define NB  64
#define NV  300
#define NH  256
#define G3  768
#define D2  512
#define COLS 1536
#define ROWS 16384

__device__ __forceinline__ float sigm(float x){ return 1.0f/(1.0f+__expf(-x)); }
__device__ __forceinline__ float tanh_(float x){ float e=__expf(2.0f*x); return 1.0f-2.0f/(e+1.0f); }
__device__ __forceinline__ float b2f(ushort u){ __bf16 t; *(ushort*)&t = u; return (float)t; }

__device__ __forceinline__ void gld_lds16(const void* g, void* l){
  __builtin_amdgcn_global_load_lds((__attribute__((address_space(1))) void*)g,
                                   (__attribute__((address_space(3))) void*)l, 16, 0, 0);
}

// shared 64x64-tile fp32 GEMM inner product: As/Bs are [k][row] so reads are float4
__device__ __forceinline__ void mm16(const float (*As)[68], const float (*Bs)[68],
                                     float acc[4][4], int ty, int tx){
  #pragma unroll
  for (int kk=0;kk<16;kk++){
    const float4 a4 = *(const float4*)&As[kk][ty*4];
    const float4 b4 = *(const float4*)&Bs[kk][tx*4];
    const float ai[4] = {a4.x,a4.y,a4.z,a4.w};
    const float bj[4] = {b4.x,b4.y,b4.z,b4.w};
    #pragma unroll
    for (int i=0;i<4;i++)
      #pragma unroll
      for (int j=0;j<4;j++)
        acc[i][j] = fmaf(ai[i], bj[j], acc[i][j]);
  }
}

// --- prep: W_hh -> bf16 MFMA B-frag layout for 8-wave k_gru ---
// idx = (((dir*8+w)*6 + nt)*8 + kf)*64 + lane ; nt = tau*2+usub
// value e: B[k][col]: col = lane&15 -> gate g = tau*256 + w*32 + usub*16 + col
//          k = kf*32 + (lane>>4)*8 + e
__global__ __launch_bounds__(256) void k_wpk(const float* __restrict__ Wf,
                                             const float* __restrict__ Wb,
                                             ushort* __restrict__ wpk){
  const int idx = blockIdx.x*256 + threadIdx.x;   // 49152
  const int l   = idx & 63;
  const int kf  = (idx >> 6) & 7;
  const int r2  = idx >> 9;
  const int nt  = r2 % 6;
  const int r3  = r2 / 6;
  const int w   = r3 & 7;
  const int dir = r3 >> 3;
  const int tau = nt >> 1, usub = nt & 1;
  const int g   = tau*256 + w*32 + usub*16 + (l & 15);
  const int kb  = kf*32 + (l >> 4)*8;
  const float* __restrict__ W = dir ? Wb : Wf;
  #pragma unroll
  for (int e=0;e<8;e++){
    __bf16 v = (__bf16)W[(size_t)g*NH + kb + e];
    wpk[(size_t)idx*8 + e] = *(ushort*)&v;
  }
}

// --- xg = gather(embed, x) @ W_ih^T + b_ih, stored bf16 [s][row][1536] ---
__global__ __launch_bounds__(256) void k_xg(const int* __restrict__ x,
    const float* __restrict__ embed,
    const float* __restrict__ Wf, const float* __restrict__ Wb,
    const float* __restrict__ bf_, const float* __restrict__ bb_,
    bf16* __restrict__ xg)
{
  __shared__ float As[16][68];
  __shared__ float Bs[16][68];
  const int tid = threadIdx.x;
  const int R0 = blockIdx.x * 64;
  const int s  = R0 >> 14;
  const int r0 = R0 & 16383;
  const int C0 = blockIdx.y * 64;
  const int dir = C0 / G3;
  const int cg0 = C0 - dir*G3;
  const float* __restrict__ W  = dir ? Wb : Wf;
  const float* __restrict__ bi = dir ? bb_ : bf_;

  const int lr = tid >> 2;
  const int lk = (tid & 3) * 4;
  const int rr = r0 + lr;
  const int bidx = rr >> 8, nidx = rr & 255;
  const int token = x[(bidx*2 + s)*SEQ + nidx];
  const float* __restrict__ arow = embed + (size_t)token * NV;
  const float* __restrict__ brow = W + (size_t)(cg0 + lr) * NV;

  const int ty = tid >> 4, tx = tid & 15;
  float acc[4][4] = {};

  for (int k0 = 0; k0 < NV; k0 += 16){
    float av[4], bv[4];
    const int ka = k0 + lk;
    if (ka + 4 <= NV){
      float4 t = *(const float4*)(arow + ka);
      av[0]=t.x; av[1]=t.y; av[2]=t.z; av[3]=t.w;
      float4 u = *(const float4*)(brow + ka);
      bv[0]=u.x; bv[1]=u.y; bv[2]=u.z; bv[3]=u.w;
    } else {
      #pragma unroll
      for (int i=0;i<4;i++){
        av[i] = (ka+i < NV) ? arow[ka+i] : 0.0f;
        bv[i] = (ka+i < NV) ? brow[ka+i] : 0.0f;
      }
    }
    __syncthreads();
    #pragma unroll
    for (int i=0;i<4;i++){ As[lk+i][lr] = av[i]; Bs[lk+i][lr] = bv[i]; }
    __syncthreads();
    mm16(As, Bs, acc, ty, tx);
  }

  #pragma unroll
  for (int i=0;i<4;i++){
    const int r = r0 + ty*4 + i;
    #pragma unroll
    for (int j=0;j<4;j++){
      const int c = C0 + tx*4 + j;
      const float v = acc[i][j] + bi[cg0 + tx*4 + j];
      xg[((size_t)s*ROWS + r)*COLS + c] = __float2bfloat16(v);
    }
  }
}

// --- GRU recurrence: 16 WGs x 512 threads (8 waves, 2/SIMD) ---
// LDS: [0,98304) weights kf=6,7 ; [98304,115200) h dbuf 2 x 16 x 528B
#define LWB 0
#define HB0 98304
__global__ __launch_bounds__(512, 2) void k_gru(const bf16* __restrict__ xg,
      const ushort* __restrict__ wpk,
      const float* __restrict__ bhhf, const float* __restrict__ bhhb,
      float* __restrict__ o2)
{
  __shared__ __align__(16) char SMEM[115200];
  const int tid = threadIdx.x, w = tid >> 6, l = tid & 63, l15 = l & 15, lg = l >> 4;
  const int wgid = blockIdx.x;
  const int chain = wgid >> 2, slice = wgid & 3;
  const int s = chain >> 1, dir = chain & 1, b0 = slice * 16;
  const int sb64 = s*64 + b0;
  const float* __restrict__ bhh = dir ? bhhb : bhhf;
  const char* wbg = (const char*)wpk + (size_t)(dir*8 + w) * 49152;
  const ushort* __restrict__ xgu = (const ushort*)xg + (size_t)s*ROWS*COLS + dir*G3;

  // stage kf=6,7 fragments to LDS (async, drained by the __syncthreads below)
  #pragma unroll
  for (int nt=0; nt<6; nt++)
    #pragma unroll
    for (int kfi=0; kfi<2; kfi++)
      gld_lds16(wbg + (size_t)(((nt*8 + 6 + kfi)*64) + l)*16,
                &SMEM[LWB + ((w*6 + nt)*2 + kfi)*1024]);

  // zero h buffer 0
  for (int k = tid; k < 2112; k += 512) ((float*)&SMEM[HB0])[k] = 0.0f;

  // resident weights kf=0..5 : 36 frags = 144 VGPRs
  bf16x8 Wr[6][6];
  #pragma unroll
  for (int nt=0; nt<6; nt++)
    #pragma unroll
    for (int kf=0; kf<6; kf++)
      Wr[nt][kf] = *(const bf16x8*)(wbg + (size_t)((nt*8 + kf)*64 + l)*16);

  float br[2], bz[2], bn[2];
  #pragma unroll
  for (int usub=0; usub<2; usub++){
    const int u = w*32 + usub*16 + l15;
    br[usub] = bhh[u]; bz[usub] = bhh[256+u]; bn[usub] = bhh[512+u];
  }

  __syncthreads();

  float hp[2][4] = {};
  const int aoff = l15*528 + lg*16;

  #pragma unroll 1
  for (int t=0; t<SEQ; t++){
    const int n = dir ? (255 - t) : t;
    const int cur = t & 1;
    const int hcur = HB0 + cur*8448, hnxt = HB0 + (cur^1)*8448;

    // prefetch this step's 24 xg gate scalars (raw u16; convert at use so the
    // waitcnt lands in the gate phase, hidden under the MFMA phase)
    ushort xv[3][2][4];
    #pragma unroll
    for (int tau=0; tau<3; tau++)
      #pragma unroll
      for (int usub=0; usub<2; usub++)
        #pragma unroll
        for (int j=0; j<4; j++)
          xv[tau][usub][j] = xgu[((size_t)(b0 + lg*4 + j)*256 + n)*1536
                                 + tau*256 + w*32 + usub*16 + l15];

    // hg = h_t @ W_hh^T (bf16 MFMA, fp32 acc) : 48 MFMA per wave
    f32x4 C[6] = {};
    #pragma unroll
    for (int kf=0; kf<6; kf++){
      const bf16x8 a = *(const bf16x8*)&SMEM[hcur + aoff + kf*64];
      #pragma unroll
      for (int nt=0; nt<6; nt++)
        C[nt] = __builtin_amdgcn_mfma_f32_16x16x32_bf16(a, Wr[nt][kf], C[nt], 0, 0, 0);
    }
    #pragma unroll
    for (int kfi=0; kfi<2; kfi++){
      const bf16x8 a = *(const bf16x8*)&SMEM[hcur + aoff + (6+kfi)*64];
      #pragma unroll
      for (int nt=0; nt<6; nt++){
        const bf16x8 wv = *(const bf16x8*)&SMEM[LWB + ((w*6+nt)*2 + kfi)*1024 + l*16];
        C[nt] = __builtin_amdgcn_mfma_f32_16x16x32_bf16(a, wv, C[nt], 0, 0, 0);
      }
    }

    // gates + h update (fp32 carried state in regs); C[tau*2+usub][j]
    #pragma unroll
    for (int usub=0; usub<2; usub++){
      #pragma unroll
      for (int j=0; j<4; j++){
        const int rb = lg*4 + j;
        const int u = w*32 + usub*16 + l15;
        const float xr = b2f(xv[0][usub][j]);
        const float xz = b2f(xv[1][usub][j]);
        const float xn = b2f(xv[2][usub][j]);
        const float r  = sigm(xr + C[usub][j]   + br[usub]);
        const float z  = sigm(xz + C[2+usub][j] + bz[usub]);
        const float nn = tanh_(xn + r*(C[4+usub][j] + bn[usub]));
        const float h  = (1.0f - z)*nn + z*hp[usub][j];
        hp[usub][j] = h;
        *(__bf16*)&SMEM[hnxt + rb*528 + u*2] = (__bf16)h;
        o2[((size_t)(sb64 + rb)*256 + n)*512 + dir*256 + u] = h;
      }
    }
    __syncthreads();
  }
}

// --- scores[sb][n][m] = <o2[n], o2[m]> - (n-m)^2/sigma ---
__global__ __launch_bounds__(256) void k_scores(const float* __restrict__ o2,
                                                float* __restrict__ sc){
  __shared__ float An[16][68];
  __shared__ float Am[16][68];
  const int tid = threadIdx.x;
  const int sb = blockIdx.z;
  const int n0 = blockIdx.x*64, m0 = blockIdx.y*64;
  const float* __restrict__ O = o2 + (size_t)sb*SEQ*D2;
  const int lr = tid >> 2, lk = (tid & 3)*4;
  const int ty = tid >> 4, tx = tid & 15;
  float acc[4][4] = {};
  for (int k0=0;k0<D2;k0+=16){
    const float4 a = *(const float4*)(O + (size_t)(n0+lr)*D2 + k0 + lk);
    const float4 b = *(const float4*)(O + (size_t)(m0+lr)*D2 + k0 + lk);
    __syncthreads();
    An[lk+0][lr]=a.x; An[lk+1][lr]=a.y; An[lk+2][lr]=a.z; An[lk+3][lr]=a.w;
    Am[lk+0][lr]=b.x; Am[lk+1][lr]=b.y; Am[lk+2][lr]=b.z; Am[lk+3][lr]=b.w;
    __syncthreads();
    mm16(An, Am, acc, ty, tx);
  }
  #pragma unroll
  for (int i=0;i<4;i++){
    const int nn = n0 + ty*4 + i;
    #pragma unroll
    for (int j=0;j<4;j++){
      const int mm = m0 + tx*4 + j;
      const float d = (float)(nn - mm);
      sc[((size_t)sb*SEQ + nn)*SEQ + mm] = acc[i][j] - d*d*(1.0f/0.95f);
    }
  }
}

// --- row softmax over last dim (256), one wave per row, in place ---
__global__ __launch_bounds__(256) void k_softmax(float* __restrict__ sc){
  const int row = blockIdx.x*4 + (threadIdx.x >> 6);
  const int lane = threadIdx.x & 63;
  float4* R = (float4*)(sc + (size_t)row*SEQ);
  float4 v = R[lane];
  float m = fmaxf(fmaxf(v.x,v.y), fmaxf(v.z,v.w));
  #pragma unroll
  for (int off=32; off; off>>=1) m = fmaxf(m, __shfl_xor(m, off));
  float4 e;
  e.x = __expf(v.x-m); e.y = __expf(v.y-m); e.z = __expf(v.z-m); e.w = __expf(v.w-m);
  float ssum = e.x+e.y+e.z+e.w;
  #pragma unroll
  for (int off=32; off; off>>=1) ssum += __shfl_xor(ssum, off);
  const float inv = 1.0f/ssum;
  e.x*=inv; e.y*=inv; e.z*=inv; e.w*=inv;
  R[lane] = e;
}

// --- o5 = P @ o2 per (s,b) ---
__global__ __launch_bounds__(256) void k_o5(const float* __restrict__ sc,
                                            const float* __restrict__ o2,
                                            float* __restrict__ o5){
  __shared__ float As[16][68];
  __shared__ float Bs[16][68];
  const int tid = threadIdx.x;
  const int sb = blockIdx.z;
  const int n0 = blockIdx.x*64, d0 = blockIdx.y*64;
  const float* __restrict__ P = sc + (size_t)sb*SEQ*SEQ;
  const float* __restrict__ O = o2 + (size_t)sb*SEQ*D2;
  const int lr = tid >> 2, lk = (tid & 3)*4;
  const int lc = tid & 63, lq = tid >> 6;
  const int ty = tid >> 4, tx = tid & 15;
  float acc[4][4] = {};
  for (int k0=0;k0<SEQ;k0+=16){
    const float4 a = *(const float4*)(P + (size_t)(n0+lr)*SEQ + k0 + lk);
    float bv[4];
    #pragma unroll
    for (int i=0;i<4;i++) bv[i] = O[(size_t)(k0 + lq*4 + i)*D2 + d0 + lc];
    __syncthreads();
    As[lk+0][lr]=a.x; As[lk+1][lr]=a.y; As[lk+2][lr]=a.z; As[lk+3][lr]=a.w;
    #pragma unroll
    for (int i=0;i<4;i++) Bs[lq*4+i][lc] = bv[i];
    __syncthreads();
    mm16(As, Bs, acc, ty, tx);
  }
  #pragma unroll
  for (int i=0;i<4;i++)
    #pragma unroll
    for (int j=0;j<4;j++)
      o5[(size_t)sb*SEQ*D2 + (size_t)(n0+ty*4+i)*D2 + d0+tx*4+j] = acc[i][j];
}

// --- mean/max pool over n ---
__global__ __launch_bounds__(256) void k_pool(const float* __restrict__ o5,
                                              float* __restrict__ feats){
  const int idx = blockIdx.x*256 + threadIdx.x;
  const int sb = idx >> 9, d = idx & 511;
  const float* __restrict__ P = o5 + (size_t)sb*SEQ*D2 + d;
  float sum = 0.0f, mx = -1e30f;
  for (int n=0;n<SEQ;n++){ const float v = P[(size_t)n*D2]; sum += v; mx = fmaxf(mx, v); }
  feats[(size_t)sb*1024 + d] = sum*(1.0f/256.0f);
  feats[(size_t)sb*1024 + 512 + d] = mx;
}

// --- z = [|fa-fb|, fa*fb] ---
__global__ __launch_bounds__(256) void k_z(const float* __restrict__ feats,
                                           float* __restrict__ Z){
  const int idx = blockIdx.x*256 + threadIdx.x;
  const int b = idx >> 11, k = idx & 2047;
  const int j = (k < 1024) ? k : (k - 1024);
  const float fa = feats[(size_t)b*1024 + j];
  const float fb = feats[(size_t)(64 + b)*1024 + j];
  Z[idx] = (k < 1024) ? fabsf(fa - fb) : fa*fb;
}

// --- h1 = relu(Z @ fc1_w^T + fc1_b) ---
__global__ __launch_bounds__(256) void k_fc1(const float* __restrict__ Z,
                                             const float* __restrict__ w,
                                             const float* __restrict__ bias,
                                             float* __restrict__ h1){
  __shared__ float As[16][68];
  __shared__ float Bs[16][68];
  const int tid = threadIdx.x;
  const int c0 = blockIdx.x*64;
  const int lr = tid >> 2, lk = (tid & 3)*4;
  const int ty = tid >> 4, tx = tid & 15;
  float acc[4][4] = {};
  for (int k0=0;k0<2048;k0+=16){
    const float4 a = *(const float4*)(Z + (size_t)lr*2048 + k0 + lk);
    const float4 b = *(const float4*)(w + (size_t)(c0+lr)*2048 + k0 + lk);
    __syncthreads();
    As[lk+0][lr]=a.x; As[lk+1][lr]=a.y; As[lk+2][lr]=a.z; As[lk+3][lr]=a.w;
    Bs[lk+0][lr]=b.x; Bs[lk+1][lr]=b.y; Bs[lk+2][lr]=b.z; Bs[lk+3][lr]=b.w;
    __syncthreads();
    mm16(As, Bs, acc, ty, tx);
  }
  #pragma unroll
  for (int i=0;i<4;i++)
    #pragma unroll
    for (int j=0;j<4;j++)
      h1[(size_t)(ty*4+i)*512 + c0+tx*4+j] = fmaxf(acc[i][j] + bias[c0+tx*4+j], 0.0f);
}

// --- out[b] = sigmoid(h1[b] . fc2_w + fc2_b) ---
__global__ __launch_bounds__(256) void k_fc2(const float* __restrict__ h1,
                                             const float* __restrict__ w2,
                                             const float* __restrict__ b2,
                                             float* __restrict__ out){
  __shared__ float red[256];
  const int b = blockIdx.x, tid = threadIdx.x;
  float p = h1[(size_t)b*512 + tid]*w2[tid] + h1[(size_t)b*512 + 256 + tid]*w2[256 + tid];
  red[tid] = p; __syncthreads();
  for (int s2=128; s2; s2>>=1){ if (tid < s2) red[tid] += red[tid+s2]; __syncthreads(); }
  if (tid == 0) out[b] = 1.0f/(1.0f + __expf(-(red[0] + b2[0])));
}

extern "C" void kernel_launch(void* const* d_in, const int* in_sizes, int n_in,
                              void* d_out, int out_size, void* d_ws, size_t ws_size,
                              hipStream_t stream){
  const int*   x     = (const int*)d_in[0];
  const float* embed = (const float*)d_in[1];
  const float* Wihf  = (const float*)d_in[2];
  const float* Whhf  = (const float*)d_in[3];
  const float* bihf  = (const float*)d_in[4];
  const float* bhhf  = (const float*)d_in[5];
  const float* Wihb  = (const float*)d_in[6];
  const float* Whhb  = (const float*)d_in[7];
  const float* bihb  = (const float*)d_in[8];
  const float* bhhb  = (const float*)d_in[9];
  const float* fc1w  = (const float*)d_in[10];
  const float* fc1b  = (const float*)d_in[11];
  const float* fc2w  = (const float*)d_in[12];
  const float* fc2b  = (const float*)d_in[13];
  float* out = (float*)d_out;

  char* ws = (char*)d_ws;
  // layout (bytes):
  //   [0, 100663296)           xg bf16 [2][16384][1536]  (dead after k_gru)
  //     alias [0, 33554432)    scores fp32 [128][256][256]
  //     alias [33554432, 100663296) o5 fp32 [128][256][512]
  //   [100663296, 167772160)   o2 fp32 [128][256][512]
  //   [167772160, +786432)     Wpk bf16 frag-packed [2][8][6][8][64][8]
  //   [169345024, 169869312)   feats fp32 [128][1024]
  //   [169869312, 170393600)   Z fp32 [64][2048]
  //   [170393600, 170524672)   h1 fp32 [64][512]
  bf16*   xg     = (bf16*)ws;
  float*  scores = (float*)ws;
  float*  o5     = (float*)(ws + 33554432);
  float*  o2     = (float*)(ws + 100663296);
  ushort* Wpk    = (ushort*)(ws + 167772160);
  float*  feats  = (float*)(ws + 169345024);
  float*  Z      = (float*)(ws + 169869312);
  float*  h1     = (float*)(ws + 170393600);

  k_wpk<<<192, 256, 0, stream>>>(Whhf, Whhb, Wpk);
  k_xg<<<dim3(512, 24), 256, 0, stream>>>(x, embed, Wihf, Wihb, bihf, bihb, xg);
  k_gru<<<16, 512, 0, stream>>>(xg, Wpk, bhhf, bhhb, o2);
  k_scores<<<dim3(4, 4, 128), 256, 0, stream>>>(o2, scores);
  k_softmax<<<8192, 256, 0, stream>>>(scores);
  k_o5<<<dim3(4, 8, 128), 256, 0, stream>>>(scores, o2, o5);
  k_pool<<<256, 256, 0, stream>>>(o5, feats);
  k_z<<<512, 256, 0, stream>>>(feats, Z);
  k_fc1<<<8, 256, 0, stream>>>(Z, fc1w, fc1b, h1);
  k_fc2<<<64, 256, 0, stream>>>(h1, fc2w, fc2b, out);
}

// Round 4
// 966.111 us; speedup vs baseline: 2.9416x; 1.5643x over previous
//
#include <hip/hip_runtime.h>
#include <hip/hip_bf16.h>

typedef __hip_bfloat16 bf16;
typedef __bf16 bf16x8 __attribute__((ext_vector_type(8)));
typedef float f32x4 __attribute__((ext_vector_type(4)));

#define SEQ 256
#define NB  64
#define NV  300
#define NH  256
#define G3  768
#define D2  512

__device__ __forceinline__ float sigm(float x){ return 1.0f/(1.0f+__expf(-x)); }
__device__ __forceinline__ float tanh_(float x){ float e=__expf(2.0f*x); return 1.0f-2.0f/(e+1.0f); }
__device__ __forceinline__ ushort f2bs(float f){ __bf16 t = (__bf16)f; return *(ushort*)&t; }
__device__ __forceinline__ float u2f(uint u){ return __uint_as_float(u); }

__device__ __forceinline__ void gld_lds16(const void* g, void* l){
  __builtin_amdgcn_global_load_lds((__attribute__((address_space(1))) void*)g,
                                   (__attribute__((address_space(3))) void*)l, 16, 0, 0);
}

// fp32 64x64 tile helper (still used by fc1)
__device__ __forceinline__ void mm16(const float (*As)[68], const float (*Bs)[68],
                                     float acc[4][4], int ty, int tx){
  #pragma unroll
  for (int kk=0;kk<16;kk++){
    const float4 a4 = *(const float4*)&As[kk][ty*4];
    const float4 b4 = *(const float4*)&Bs[kk][tx*4];
    const float ai[4] = {a4.x,a4.y,a4.z,a4.w};
    const float bj[4] = {b4.x,b4.y,b4.z,b4.w};
    #pragma unroll
    for (int i=0;i<4;i++)
      #pragma unroll
      for (int j=0;j<4;j++)
        acc[i][j] = fmaf(ai[i], bj[j], acc[i][j]);
  }
}

// === prep: gathered embedding -> bf16, K padded 300->320 ===
__global__ __launch_bounds__(320) void k_emb(const int* __restrict__ x,
                                             const float* __restrict__ embed,
                                             ushort* __restrict__ E){
  const int t = threadIdx.x;
  const int rsub = t / 80, c4 = t - rsub*80;
  const int row = blockIdx.x*4 + rsub;           // 32768 rows = s*16384 + b*256 + n
  const int s = row >> 14, b = (row >> 8) & 63, n = row & 255;
  const int token = x[(b*2 + s)*SEQ + n];
  const int k = c4*4;
  float4 v = make_float4(0,0,0,0);
  if (k < NV) v = *(const float4*)(embed + (size_t)token*NV + k);
  ushort4 o;
  o.x = f2bs(v.x); o.y = f2bs(v.y); o.z = f2bs(v.z); o.w = f2bs(v.w);
  *(ushort4*)(E + (size_t)row*320 + k) = o;
}

// === prep: W_ih (f then b) -> bf16 [1536][320] ===
__global__ __launch_bounds__(320) void k_wih(const float* __restrict__ Wf,
                                             const float* __restrict__ Wb,
                                             ushort* __restrict__ W16){
  const int t = threadIdx.x;
  const int rsub = t / 80, c4 = t - rsub*80;
  const int g = blockIdx.x*4 + rsub;             // 0..1535
  const int dir = g >= G3;
  const int gw = g - dir*G3;
  const float* __restrict__ W = dir ? Wb : Wf;
  const int k = c4*4;
  float4 v = make_float4(0,0,0,0);
  if (k < NV) v = *(const float4*)(W + (size_t)gw*NV + k);
  ushort4 o;
  o.x = f2bs(v.x); o.y = f2bs(v.y); o.z = f2bs(v.z); o.w = f2bs(v.w);
  *(ushort4*)(W16 + (size_t)g*320 + k) = o;
}

// === prep: W_hh -> bf16 MFMA B-frag layout (verified round 3) ===
__global__ __launch_bounds__(256) void k_wpk(const float* __restrict__ Wf,
                                             const float* __restrict__ Wb,
                                             ushort* __restrict__ wpk){
  const int idx = blockIdx.x*256 + threadIdx.x;   // 49152
  const int l   = idx & 63;
  const int kf  = (idx >> 6) & 7;
  const int r2  = idx >> 9;
  const int nt  = r2 % 6;
  const int r3  = r2 / 6;
  const int w   = r3 & 7;
  const int dir = r3 >> 3;
  const int tau = nt >> 1, usub = nt & 1;
  const int g   = tau*256 + w*32 + usub*16 + (l & 15);
  const int kb  = kf*32 + (l >> 4)*8;
  const float* __restrict__ W = dir ? Wb : Wf;
  #pragma unroll
  for (int e=0;e<8;e++)
    wpk[(size_t)idx*8 + e] = f2bs(W[(size_t)g*NH + kb + e]);
}

// === xg GEMM (MFMA): E[32768x320] @ W16^T -> packed xg bf16, biases folded ===
// packed xg row (3072B): dir*1536 + tau*512 + ((u>>5)*16 + (u&15))*4 + ((u>>4)&1)*2
__global__ __launch_bounds__(256) void k_xgm(const ushort* __restrict__ E,
    const ushort* __restrict__ W16,
    const float* __restrict__ bihf, const float* __restrict__ bihb,
    const float* __restrict__ bhhf, const float* __restrict__ bhhb,
    char* __restrict__ xgp)
{
  __shared__ __align__(16) char As[10240];   // [128 rows][80B] (32k bf16 + pad)
  __shared__ __align__(16) char Bs[10240];
  const int tid = threadIdx.x, w = tid >> 6, l = tid & 63, l15 = l & 15, lg = l >> 4;
  const int r0 = blockIdx.x * 128;
  const int c0 = blockIdx.y * 128;
  const int dir = (c0 >= G3);
  const int cw0 = c0 - dir*G3;
  const float* __restrict__ bih = dir ? bihb : bihf;
  const float* __restrict__ bhh = dir ? bhhb : bhhf;

  const int srow = tid >> 1, sc = (tid & 1)*32;
  f32x4 acc[2][8] = {};

  for (int ks = 0; ks < 10; ks++){
    const uint4 a0 = *(const uint4*)((const char*)E + (size_t)(r0+srow)*640 + ks*64 + sc);
    const uint4 a1 = *(const uint4*)((const char*)E + (size_t)(r0+srow)*640 + ks*64 + sc + 16);
    const uint4 b0 = *(const uint4*)((const char*)W16 + (size_t)(c0+srow)*640 + ks*64 + sc);
    const uint4 b1 = *(const uint4*)((const char*)W16 + (size_t)(c0+srow)*640 + ks*64 + sc + 16);
    __syncthreads();
    *(uint4*)&As[srow*80 + sc] = a0;
    *(uint4*)&As[srow*80 + sc + 16] = a1;
    *(uint4*)&Bs[srow*80 + sc] = b0;
    *(uint4*)&Bs[srow*80 + sc + 16] = b1;
    __syncthreads();
    bf16x8 am[2], bn[8];
    #pragma unroll
    for (int mm=0;mm<2;mm++) am[mm] = *(const bf16x8*)&As[(w*32 + mm*16 + l15)*80 + lg*16];
    #pragma unroll
    for (int nt=0;nt<8;nt++)  bn[nt] = *(const bf16x8*)&Bs[(nt*16 + l15)*80 + lg*16];
    #pragma unroll
    for (int mm=0;mm<2;mm++)
      #pragma unroll
      for (int nt=0;nt<8;nt++)
        acc[mm][nt] = __builtin_amdgcn_mfma_f32_16x16x32_bf16(am[mm], bn[nt], acc[mm][nt], 0,0,0);
  }

  #pragma unroll
  for (int nt=0;nt<8;nt++){
    const int cwb = cw0 + nt*16;
    const int tau = cwb >> 8;
    const int u   = cwb & 255;
    const int usub = (u >> 4) & 1;
    const int wu   = u >> 5;
    const size_t boff = (size_t)dir*1536 + tau*512 + (wu*16 + l15)*4 + usub*2;
    const float bias = bih[cwb + l15] + ((tau < 2) ? bhh[cwb + l15] : 0.0f);
    #pragma unroll
    for (int mm=0;mm<2;mm++)
      #pragma unroll
      for (int j=0;j<4;j++){
        const int row = r0 + w*32 + mm*16 + lg*4 + j;
        *(ushort*)(xgp + (size_t)row*3072 + boff) = f2bs(acc[mm][nt][j] + bias);
      }
  }
}

// === GRU recurrence: 16 WGs x 512 threads; weight-resident MFMA ===
// LDS: [0,98304) weights kf=6,7 ; [98304, 115712) h dbuf 2 x 16 x 544B
#define HB0 98304
#define HSTR 544
__global__ __launch_bounds__(512, 2) void k_gru(const char* __restrict__ xgp,
      const ushort* __restrict__ wpk,
      const float* __restrict__ bhhf, const float* __restrict__ bhhb,
      ushort* __restrict__ o2b)
{
  __shared__ __align__(16) char SMEM[115712];
  const int tid = threadIdx.x, w = tid >> 6, l = tid & 63, l15 = l & 15, lg = l >> 4;
  const int wgid = blockIdx.x;
  const int chain = wgid >> 2, slice = wgid & 3;
  const int s = chain >> 1, dir = chain & 1, b0 = slice * 16;
  const int sb64 = s*64 + b0;
  const float* __restrict__ bhh = dir ? bhhb : bhhf;
  const char* wbg = (const char*)wpk + (size_t)(dir*8 + w) * 49152;

  #pragma unroll
  for (int nt=0; nt<6; nt++)
    #pragma unroll
    for (int kfi=0; kfi<2; kfi++)
      gld_lds16(wbg + (size_t)(((nt*8 + 6 + kfi)*64) + l)*16,
                &SMEM[((w*6 + nt)*2 + kfi)*1024]);

  for (int k = tid; k < 2176; k += 512) ((float*)&SMEM[HB0])[k] = 0.0f;

  bf16x8 Wr[6][6];
  #pragma unroll
  for (int nt=0; nt<6; nt++)
    #pragma unroll
    for (int kf=0; kf<6; kf++)
      Wr[nt][kf] = *(const bf16x8*)(wbg + (size_t)((nt*8 + kf)*64 + l)*16);

  float bn2[2];
  #pragma unroll
  for (int usub=0; usub<2; usub++)
    bn2[usub] = bhh[512 + w*32 + usub*16 + l15];

  const int n0 = dir ? 255 : 0;
  const int sstep = dir ? -3072 : 3072;
  const int ostep = dir ? -1024 : 1024;
  const char* xp[4];
  char* op[4];
  #pragma unroll
  for (int j=0;j<4;j++){
    const int rb = lg*4 + j;
    xp[j] = xgp + ((size_t)s*16384 + (size_t)(b0+rb)*256 + n0)*3072
              + dir*1536 + (w*16 + l15)*4;
    op[j] = (char*)o2b + ((size_t)(sb64+rb)*256 + n0)*1024 + dir*512 + (w*32 + l15)*2;
  }

  __syncthreads();

  float hp[2][4] = {};
  ushort ho[2][4];
  const int aoff = l15*HSTR + lg*16;

  #pragma unroll 1
  for (int t=0; t<SEQ; t++){
    const int cur = t & 1;
    const int hcur = HB0 + cur*8704, hnxt = HB0 + (cur^1)*8704;

    // this step's gate inputs: 3 aligned dwords per row, imm offsets
    uint q[3][4];
    #pragma unroll
    for (int j=0;j<4;j++){
      q[0][j] = *(const uint*)(xp[j]);
      q[1][j] = *(const uint*)(xp[j] + 512);
      q[2][j] = *(const uint*)(xp[j] + 1024);
      xp[j] += sstep;
    }
    // deferred o2 stores (previous step's h) overlap the MFMA phase
    if (t){
      #pragma unroll
      for (int j=0;j<4;j++){
        *(ushort*)(op[j])      = ho[0][j];
        *(ushort*)(op[j] + 32) = ho[1][j];
        op[j] += ostep;
      }
    }

    f32x4 C[6] = {};
    #pragma unroll
    for (int kf=0; kf<6; kf++){
      const bf16x8 a = *(const bf16x8*)&SMEM[hcur + aoff + kf*64];
      #pragma unroll
      for (int nt=0; nt<6; nt++)
        C[nt] = __builtin_amdgcn_mfma_f32_16x16x32_bf16(a, Wr[nt][kf], C[nt], 0, 0, 0);
    }
    #pragma unroll
    for (int kfi=0; kfi<2; kfi++){
      const bf16x8 a = *(const bf16x8*)&SMEM[hcur + aoff + (6+kfi)*64];
      #pragma unroll
      for (int nt=0; nt<6; nt++){
        const bf16x8 wv = *(const bf16x8*)&SMEM[((w*6+nt)*2 + kfi)*1024 + l*16];
        C[nt] = __builtin_amdgcn_mfma_f32_16x16x32_bf16(a, wv, C[nt], 0, 0, 0);
      }
    }

    #pragma unroll
    for (int usub=0; usub<2; usub++){
      #pragma unroll
      for (int j=0; j<4; j++){
        const int rb = lg*4 + j;
        const float xr = u2f(usub ? (q[0][j] & 0xffff0000u) : (q[0][j] << 16));
        const float xz = u2f(usub ? (q[1][j] & 0xffff0000u) : (q[1][j] << 16));
        const float xn = u2f(usub ? (q[2][j] & 0xffff0000u) : (q[2][j] << 16));
        const float r  = sigm(xr + C[usub][j]);
        const float z  = sigm(xz + C[2+usub][j]);
        const float nn = tanh_(xn + r*(C[4+usub][j] + bn2[usub]));
        const float h  = (1.0f - z)*nn + z*hp[usub][j];
        hp[usub][j] = h;
        const ushort hb = f2bs(h);
        ho[usub][j] = hb;
        *(ushort*)&SMEM[hnxt + rb*HSTR + (w*32 + usub*16 + l15)*2] = hb;
      }
    }
    __syncthreads();
  }
  #pragma unroll
  for (int j=0;j<4;j++){
    *(ushort*)(op[j])      = ho[0][j];
    *(ushort*)(op[j] + 32) = ho[1][j];
  }
}

// === transpose o2b -> o2t (bf16), per sb 64x64 tiles ===
__global__ __launch_bounds__(256) void k_tr(const ushort* __restrict__ o2b,
                                            ushort* __restrict__ o2t){
  __shared__ __align__(16) char Ts[64*144];
  const int t = threadIdx.x;
  const int sb = blockIdx.z;
  const int n0 = blockIdx.x*64, d0 = blockIdx.y*64;
  const char* src = (const char*)o2b + (size_t)sb*262144;
  char* dst = (char*)o2t + (size_t)sb*262144;
  const int r = t >> 3, ch = t & 7;
  #pragma unroll
  for (int p=0;p<2;p++){
    const int row = r + p*32;
    const uint4 v = *(const uint4*)(src + (size_t)(n0+row)*1024 + d0*2 + ch*16);
    *(uint4*)&Ts[row*144 + ch*16] = v;
  }
  __syncthreads();
  #pragma unroll
  for (int p=0;p<2;p++){
    const int d = r + p*32;
    uint o[4];
    #pragma unroll
    for (int i=0;i<4;i++){
      const uint lo = *(const ushort*)&Ts[(ch*8 + 2*i)*144 + d*2];
      const uint hi = *(const ushort*)&Ts[(ch*8 + 2*i + 1)*144 + d*2];
      o[i] = lo | (hi << 16);
    }
    *(uint4*)(dst + (size_t)(d0+d)*512 + n0*2 + ch*16) = *(uint4*)o;
  }
}

// === scores (MFMA): o2b @ o2b^T - dist ===
__global__ __launch_bounds__(256) void k_scores(const ushort* __restrict__ o2b,
                                                float* __restrict__ sc){
  __shared__ __align__(16) char As[64*144];
  __shared__ __align__(16) char Bs[64*144];
  const int tid = threadIdx.x, w = tid >> 6, l = tid & 63, l15 = l & 15, lg = l >> 4;
  const int sb = blockIdx.z;
  const int n0 = blockIdx.x*64, m0 = blockIdx.y*64;
  const char* ob = (const char*)o2b + (size_t)sb*262144;
  const int srow = tid >> 2, scf = (tid & 3)*16;
  f32x4 acc[4] = {};
  for (int it=0; it<8; it++){
    const int k0 = it*64;
    const uint4 a0 = *(const uint4*)(ob + (size_t)(n0+srow)*1024 + k0*2 + scf);
    const uint4 a1 = *(const uint4*)(ob + (size_t)(n0+srow)*1024 + k0*2 + scf + 64);
    const uint4 b0 = *(const uint4*)(ob + (size_t)(m0+srow)*1024 + k0*2 + scf);
    const uint4 b1 = *(const uint4*)(ob + (size_t)(m0+srow)*1024 + k0*2 + scf + 64);
    __syncthreads();
    *(uint4*)&As[srow*144 + scf] = a0;
    *(uint4*)&As[srow*144 + scf + 64] = a1;
    *(uint4*)&Bs[srow*144 + scf] = b0;
    *(uint4*)&Bs[srow*144 + scf + 64] = b1;
    __syncthreads();
    #pragma unroll
    for (int ks=0; ks<2; ks++){
      const bf16x8 a = *(const bf16x8*)&As[(w*16 + l15)*144 + ks*64 + lg*16];
      #pragma unroll
      for (int nt=0; nt<4; nt++){
        const bf16x8 b = *(const bf16x8*)&Bs[(nt*16 + l15)*144 + ks*64 + lg*16];
        acc[nt] = __builtin_amdgcn_mfma_f32_16x16x32_bf16(a, b, acc[nt], 0, 0, 0);
      }
    }
  }
  #pragma unroll
  for (int nt=0; nt<4; nt++)
    #pragma unroll
    for (int j=0; j<4; j++){
      const int n = n0 + w*16 + lg*4 + j;
      const int m = m0 + nt*16 + l15;
      const float d = (float)(n - m);
      sc[((size_t)sb*SEQ + n)*SEQ + m] = acc[nt][j] - d*d*(1.0f/0.95f);
    }
}

// === softmax rows -> P bf16 ===
__global__ __launch_bounds__(256) void k_softmax(const float* __restrict__ sc,
                                                 ushort* __restrict__ P){
  const int row = blockIdx.x*4 + (threadIdx.x >> 6);
  const int lane = threadIdx.x & 63;
  const float4 v = *(const float4*)(sc + (size_t)row*SEQ + lane*4);
  float m = fmaxf(fmaxf(v.x,v.y), fmaxf(v.z,v.w));
  #pragma unroll
  for (int off=32; off; off>>=1) m = fmaxf(m, __shfl_xor(m, off));
  float4 e;
  e.x = __expf(v.x-m); e.y = __expf(v.y-m); e.z = __expf(v.z-m); e.w = __expf(v.w-m);
  float ssum = e.x+e.y+e.z+e.w;
  #pragma unroll
  for (int off=32; off; off>>=1) ssum += __shfl_xor(ssum, off);
  const float inv = 1.0f/ssum;
  uint2 o;
  o.x = (uint)f2bs(e.x*inv) | ((uint)f2bs(e.y*inv) << 16);
  o.y = (uint)f2bs(e.z*inv) | ((uint)f2bs(e.w*inv) << 16);
  *(uint2*)((char*)P + (size_t)row*512 + lane*8) = o;
}

// === o5 (MFMA): P @ o2  (B from o2t) ===
__global__ __launch_bounds__(256) void k_o5(const ushort* __restrict__ P,
                                            const ushort* __restrict__ o2t,
                                            float* __restrict__ o5){
  __shared__ __align__(16) char As[64*144];
  __shared__ __align__(16) char Bs[64*144];
  const int tid = threadIdx.x, w = tid >> 6, l = tid & 63, l15 = l & 15, lg = l >> 4;
  const int sb = blockIdx.z;
  const int n0 = blockIdx.x*64, d0 = blockIdx.y*64;
  const char* pa = (const char*)P + (size_t)sb*131072;
  const char* pb = (const char*)o2t + (size_t)sb*262144;
  const int srow = tid >> 2, scf = (tid & 3)*16;
  f32x4 acc[4] = {};
  for (int it=0; it<4; it++){
    const int k0 = it*64;
    const uint4 a0 = *(const uint4*)(pa + (size_t)(n0+srow)*512 + k0*2 + scf);
    const uint4 a1 = *(const uint4*)(pa + (size_t)(n0+srow)*512 + k0*2 + scf + 64);
    const uint4 b0 = *(const uint4*)(pb + (size_t)(d0+srow)*512 + k0*2 + scf);
    const uint4 b1 = *(const uint4*)(pb + (size_t)(d0+srow)*512 + k0*2 + scf + 64);
    __syncthreads();
    *(uint4*)&As[srow*144 + scf] = a0;
    *(uint4*)&As[srow*144 + scf + 64] = a1;
    *(uint4*)&Bs[srow*144 + scf] = b0;
    *(uint4*)&Bs[srow*144 + scf + 64] = b1;
    __syncthreads();
    #pragma unroll
    for (int ks=0; ks<2; ks++){
      const bf16x8 a = *(const bf16x8*)&As[(w*16 + l15)*144 + ks*64 + lg*16];
      #pragma unroll
      for (int nt=0; nt<4; nt++){
        const bf16x8 b = *(const bf16x8*)&Bs[(nt*16 + l15)*144 + ks*64 + lg*16];
        acc[nt] = __builtin_amdgcn_mfma_f32_16x16x32_bf16(a, b, acc[nt], 0, 0, 0);
      }
    }
  }
  #pragma unroll
  for (int nt=0; nt<4; nt++)
    #pragma unroll
    for (int j=0; j<4; j++){
      const int n = n0 + w*16 + lg*4 + j;
      const int d = d0 + nt*16 + l15;
      o5[(size_t)sb*131072 + (size_t)n*D2 + d] = acc[nt][j];
    }
}

// === mean/max pool ===
__global__ __launch_bounds__(256) void k_pool(const float* __restrict__ o5,
                                              float* __restrict__ feats){
  const int idx = blockIdx.x*256 + threadIdx.x;
  const int sb = idx >> 9, d = idx & 511;
  const float* __restrict__ Pp = o5 + (size_t)sb*SEQ*D2 + d;
  float sum = 0.0f, mx = -1e30f;
  for (int n=0;n<SEQ;n++){ const float v = Pp[(size_t)n*D2]; sum += v; mx = fmaxf(mx, v); }
  feats[(size_t)sb*1024 + d] = sum*(1.0f/256.0f);
  feats[(size_t)sb*1024 + 512 + d] = mx;
}

__global__ __launch_bounds__(256) void k_z(const float* __restrict__ feats,
                                           float* __restrict__ Z){
  const int idx = blockIdx.x*256 + threadIdx.x;
  const int b = idx >> 11, k = idx & 2047;
  const int j = (k < 1024) ? k : (k - 1024);
  const float fa = feats[(size_t)b*1024 + j];
  const float fb = feats[(size_t)(64 + b)*1024 + j];
  Z[idx] = (k < 1024) ? fabsf(fa - fb) : fa*fb;
}

__global__ __launch_bounds__(256) void k_fc1(const float* __restrict__ Z,
                                             const float* __restrict__ w,
                                             const float* __restrict__ bias,
                                             float* __restrict__ h1){
  __shared__ float As[16][68];
  __shared__ float Bs[16][68];
  const int tid = threadIdx.x;
  const int c0 = blockIdx.x*64;
  const int lr = tid >> 2, lk = (tid & 3)*4;
  const int ty = tid >> 4, tx = tid & 15;
  float acc[4][4] = {};
  for (int k0=0;k0<2048;k0+=16){
    const float4 a = *(const float4*)(Z + (size_t)lr*2048 + k0 + lk);
    const float4 b = *(const float4*)(w + (size_t)(c0+lr)*2048 + k0 + lk);
    __syncthreads();
    As[lk+0][lr]=a.x; As[lk+1][lr]=a.y; As[lk+2][lr]=a.z; As[lk+3][lr]=a.w;
    Bs[lk+0][lr]=b.x; Bs[lk+1][lr]=b.y; Bs[lk+2][lr]=b.z; Bs[lk+3][lr]=b.w;
    __syncthreads();
    mm16(As, Bs, acc, ty, tx);
  }
  #pragma unroll
  for (int i=0;i<4;i++)
    #pragma unroll
    for (int j=0;j<4;j++)
      h1[(size_t)(ty*4+i)*512 + c0+tx*4+j] = fmaxf(acc[i][j] + bias[c0+tx*4+j], 0.0f);
}

__global__ __launch_bounds__(256) void k_fc2(const float* __restrict__ h1,
                                             const float* __restrict__ w2,
                                             const float* __restrict__ b2,
                                             float* __restrict__ out){
  __shared__ float red[256];
  const int b = blockIdx.x, tid = threadIdx.x;
  float p = h1[(size_t)b*512 + tid]*w2[tid] + h1[(size_t)b*512 + 256 + tid]*w2[256 + tid];
  red[tid] = p; __syncthreads();
  for (int s2=128; s2; s2>>=1){ if (tid < s2) red[tid] += red[tid+s2]; __syncthreads(); }
  if (tid == 0) out[b] = 1.0f/(1.0f + __expf(-(red[0] + b2[0])));
}

extern "C" void kernel_launch(void* const* d_in, const int* in_sizes, int n_in,
                              void* d_out, int out_size, void* d_ws, size_t ws_size,
                              hipStream_t stream){
  const int*   x     = (const int*)d_in[0];
  const float* embed = (const float*)d_in[1];
  const float* Wihf  = (const float*)d_in[2];
  const float* Whhf  = (const float*)d_in[3];
  const float* bihf  = (const float*)d_in[4];
  const float* bhhf  = (const float*)d_in[5];
  const float* Wihb  = (const float*)d_in[6];
  const float* Whhb  = (const float*)d_in[7];
  const float* bihb  = (const float*)d_in[8];
  const float* bhhb  = (const float*)d_in[9];
  const float* fc1w  = (const float*)d_in[10];
  const float* fc1b  = (const float*)d_in[11];
  const float* fc2w  = (const float*)d_in[12];
  const float* fc2b  = (const float*)d_in[13];
  float* out = (float*)d_out;

  char* ws = (char*)d_ws;
  // layout (bytes), with lifetime aliasing:
  //   [0, 100663296)            xgp packed bf16 (dead after k_gru)
  //     alias [0, 33554432)       o2t bf16 [128][512][256]     (k_tr ..k_o5)
  //     alias [33554432, 67108864) scores f32 [128][256][256]  (k_scores..k_softmax)
  //     alias [67108864, 83886080) P bf16 [128][256][256]      (k_softmax..k_o5)
  //     alias [83886080,150994944) o5 f32 [128][256][512]      (k_o5..k_pool; also overlays E,o2b tails)
  //   [100663296, 121634816)    E bf16 [32768][320]  (dead after k_xgm)
  //   [121634816, 155189248)    o2b bf16 [128][256][512] (dead after k_scores/k_tr)
  //   [155189248, 156172288)    W16 bf16 [1536][320]
  //   [156172288, 156958720)    Wpk
  //   [156958720, 157483008)    feats
  //   [157483008, 158007296)    Z
  //   [158007296, 158138368)    h1
  char*   xgp    = ws;
  ushort* o2t    = (ushort*)ws;
  float*  scores = (float*)(ws + 33554432);
  ushort* P      = (ushort*)(ws + 67108864);
  float*  o5     = (float*)(ws + 83886080);
  ushort* E      = (ushort*)(ws + 100663296);
  ushort* o2b    = (ushort*)(ws + 121634816);
  ushort* W16    = (ushort*)(ws + 155189248);
  ushort* Wpk    = (ushort*)(ws + 156172288);
  float*  feats  = (float*)(ws + 156958720);
  float*  Z      = (float*)(ws + 157483008);
  float*  h1     = (float*)(ws + 158007296);

  k_emb<<<8192, 320, 0, stream>>>(x, embed, E);
  k_wih<<<384, 320, 0, stream>>>(Wihf, Wihb, W16);
  k_wpk<<<192, 256, 0, stream>>>(Whhf, Whhb, Wpk);
  k_xgm<<<dim3(256, 12), 256, 0, stream>>>(E, W16, bihf, bihb, bhhf, bhhb, xgp);
  k_gru<<<16, 512, 0, stream>>>(xgp, Wpk, bhhf, bhhb, o2b);
  k_tr<<<dim3(4, 8, 128), 256, 0, stream>>>(o2b, o2t);
  k_scores<<<dim3(4, 4, 128), 256, 0, stream>>>(o2b, scores);
  k_softmax<<<8192, 256, 0, stream>>>(scores, P);
  k_o5<<<dim3(4, 8, 128), 256, 0, stream>>>(P, o2t, o5);
  k_pool<<<256, 256, 0, stream>>>(o5, feats);
  k_z<<<512, 256, 0, stream>>>(feats, Z);
  k_fc1<<<8, 256, 0, stream>>>(Z, fc1w, fc1b, h1);
  k_fc2<<<64, 256, 0, stream>>>(h1, fc2w, fc2b, out);
}